// Round 1
// baseline (427.012 us; speedup 1.0000x reference)
//
#include <hip/hip_runtime.h>
#include <cstddef>

// Problem constants
static constexpr int kB    = 256;   // batch
static constexpr int kS    = 196;   // att size (sequence)
static constexpr int kRNN  = 1024;  // rnn size
static constexpr int kATTH = 512;   // att hidden size

__device__ __forceinline__ float fast_tanh(float x) {
    // tanh(x) = (e^{2x}-1)/(e^{2x}+1); clamp so __expf stays finite.
    x = fminf(12.0f, fmaxf(-12.0f, x));
    float e = __expf(2.0f * x);
    return __fdividef(e - 1.0f, e + 1.0f);
}

// att_h[m,n] = sum_k h[m,k] * w[n,k] + bias[n]
// M=256 (B), N=512 (ATTH), K=1024 (RNN). 32x32 tiles, BK=32, 256 threads.
__global__ __launch_bounds__(256) void gemm_atth(
    const float* __restrict__ h, const float* __restrict__ w,
    const float* __restrict__ bias, float* __restrict__ att_h) {
    __shared__ float As[32][33];  // +1 pad: break bank conflicts
    __shared__ float Bs[32][33];
    const int bm = blockIdx.x * 32;
    const int bn = blockIdx.y * 32;
    const int tid = threadIdx.x;
    const int lrow = tid >> 3;         // 0..31
    const int lcol = (tid & 7) << 2;   // 0,4,..,28
    const int tx = tid & 31;           // n within tile
    const int ty = tid >> 5;           // 0..7 -> 4 m rows each
    float acc[4] = {0.f, 0.f, 0.f, 0.f};
    for (int k0 = 0; k0 < kRNN; k0 += 32) {
        float4 av = *(const float4*)&h[(size_t)(bm + lrow) * kRNN + k0 + lcol];
        float4 bv = *(const float4*)&w[(size_t)(bn + lrow) * kRNN + k0 + lcol];
        As[lrow][lcol + 0] = av.x; As[lrow][lcol + 1] = av.y;
        As[lrow][lcol + 2] = av.z; As[lrow][lcol + 3] = av.w;
        Bs[lrow][lcol + 0] = bv.x; Bs[lrow][lcol + 1] = bv.y;
        Bs[lrow][lcol + 2] = bv.z; Bs[lrow][lcol + 3] = bv.w;
        __syncthreads();
#pragma unroll
        for (int k = 0; k < 32; ++k) {
            float bb = Bs[tx][k];
#pragma unroll
            for (int i = 0; i < 4; ++i) acc[i] += As[ty * 4 + i][k] * bb;
        }
        __syncthreads();
    }
    const float bval = bias[bn + tx];
#pragma unroll
    for (int i = 0; i < 4; ++i)
        att_h[(size_t)(bm + ty * 4 + i) * kATTH + bn + tx] = acc[i] + bval;
}

// One block per batch element b. 1024 threads = 16 waves.
// Phase A: scores[s] = sum_a tanh(p[b,s,a] + att_h[b,a]) * w_alpha[a] + b_alpha
// Phase B: softmax over s (wave 0)
// Phase C: out[b,d] = sum_s weight[s] * att_feats[b,s,d]
__global__ __launch_bounds__(1024) void att_fused(
    const float* __restrict__ att_feats, const float* __restrict__ p_att,
    const float* __restrict__ att_h, const float* __restrict__ w_alpha,
    const float* __restrict__ b_alpha, float* __restrict__ out) {
    const int b = blockIdx.x;
    const int tid = threadIdx.x;
    const int lane = tid & 63;
    const int wave = tid >> 6;  // 0..15

    __shared__ float sScore[kS];
    __shared__ float4 sRed[3][256];  // phase-C partial sums (groups 1..3)

    // ---- Phase A: per-wave score rows; per-lane att_h/w_alpha in registers
    const int col = lane << 3;  // 8 elements per lane covers ATTH=512
    const float4 ah0 = *(const float4*)&att_h[(size_t)b * kATTH + col];
    const float4 ah1 = *(const float4*)&att_h[(size_t)b * kATTH + col + 4];
    const float4 wa0 = *(const float4*)&w_alpha[col];
    const float4 wa1 = *(const float4*)&w_alpha[col + 4];
    const float balpha = b_alpha[0];

    for (int s = wave; s < kS; s += 16) {
        const float* p = &p_att[((size_t)b * kS + s) * kATTH + col];
        const float4 p0 = *(const float4*)p;
        const float4 p1 = *(const float4*)(p + 4);
        float partial;
        partial  = fast_tanh(p0.x + ah0.x) * wa0.x;
        partial += fast_tanh(p0.y + ah0.y) * wa0.y;
        partial += fast_tanh(p0.z + ah0.z) * wa0.z;
        partial += fast_tanh(p0.w + ah0.w) * wa0.w;
        partial += fast_tanh(p1.x + ah1.x) * wa1.x;
        partial += fast_tanh(p1.y + ah1.y) * wa1.y;
        partial += fast_tanh(p1.z + ah1.z) * wa1.z;
        partial += fast_tanh(p1.w + ah1.w) * wa1.w;
#pragma unroll
        for (int off = 32; off > 0; off >>= 1)
            partial += __shfl_xor(partial, off, 64);
        if (lane == 0) sScore[s] = partial + balpha;
    }
    __syncthreads();

    // ---- Phase B: softmax over kS scores, done by wave 0
    if (tid < 64) {
        float vals[4];
        int cnt = 0;
        float m = -3.0e38f;
        for (int s = tid; s < kS; s += 64) {
            vals[cnt] = sScore[s];
            m = fmaxf(m, vals[cnt]);
            ++cnt;
        }
#pragma unroll
        for (int off = 32; off > 0; off >>= 1) m = fmaxf(m, __shfl_xor(m, off, 64));
        float sum = 0.f;
        for (int i = 0; i < cnt; ++i) { vals[i] = __expf(vals[i] - m); sum += vals[i]; }
#pragma unroll
        for (int off = 32; off > 0; off >>= 1) sum += __shfl_xor(sum, off, 64);
        const float inv = __fdividef(1.0f, sum);
        cnt = 0;
        for (int s = tid; s < kS; s += 64) { sScore[s] = vals[cnt] * inv; ++cnt; }
    }
    __syncthreads();

    // ---- Phase C: weighted sum, float4 per thread, 4-way s-split
    const int d4 = tid & 255;  // float4 index over RNN=1024
    const int sg = tid >> 8;   // 0..3
    float4 acc = {0.f, 0.f, 0.f, 0.f};
    for (int s = sg; s < kS; s += 4) {
        const float ws = sScore[s];
        const float4 v =
            *(const float4*)&att_feats[((size_t)b * kS + s) * kRNN + (d4 << 2)];
        acc.x += ws * v.x; acc.y += ws * v.y;
        acc.z += ws * v.z; acc.w += ws * v.w;
    }
    if (sg > 0) sRed[sg - 1][d4] = acc;
    __syncthreads();
    if (sg == 0) {
        const float4 r0 = sRed[0][d4];
        const float4 r1 = sRed[1][d4];
        const float4 r2 = sRed[2][d4];
        acc.x += r0.x + r1.x + r2.x;
        acc.y += r0.y + r1.y + r2.y;
        acc.z += r0.z + r1.z + r2.z;
        acc.w += r0.w + r1.w + r2.w;
        *(float4*)&out[(size_t)b * kRNN + (d4 << 2)] = acc;
    }
}

extern "C" void kernel_launch(void* const* d_in, const int* in_sizes, int n_in,
                              void* d_out, int out_size, void* d_ws, size_t ws_size,
                              hipStream_t stream) {
    const float* h         = (const float*)d_in[0];
    const float* att_feats = (const float*)d_in[1];
    const float* p_att     = (const float*)d_in[2];
    const float* w_h2att   = (const float*)d_in[3];
    const float* b_h2att   = (const float*)d_in[4];
    const float* w_alpha   = (const float*)d_in[5];
    const float* b_alpha   = (const float*)d_in[6];
    float* out = (float*)d_out;
    float* att_h = (float*)d_ws;  // 256*512 fp32 = 512 KB scratch

    dim3 g1(kB / 32, kATTH / 32);  // (8,16)
    gemm_atth<<<g1, 256, 0, stream>>>(h, w_h2att, b_h2att, att_h);
    att_fused<<<kB, 1024, 0, stream>>>(att_feats, p_att, att_h, w_alpha, b_alpha, out);
}